// Round 2
// baseline (1557.234 us; speedup 1.0000x reference)
//
#include <hip/hip_runtime.h>

// Problem constants (fixed by the reference)
#define N_NODES 100000
#define N_EDGES 1600000
#define DIM     128
#define EDIM    16
#define NLAYERS 5

typedef unsigned short ushort_t;
typedef short bf16x8 __attribute__((ext_vector_type(8)));   // 8 bf16 in 4 VGPRs
typedef float f32x4  __attribute__((ext_vector_type(4)));

__device__ __forceinline__ ushort_t f2bf(float f) {
    union { float f; unsigned int i; } c; c.f = f;
    unsigned int r = c.i + 0x7fffu + ((c.i >> 16) & 1u);   // RNE
    return (ushort_t)(r >> 16);
}

__device__ __forceinline__ bf16x8 cvt8(f32x4 a, f32x4 b) {
    bf16x8 r;
    r[0] = (short)f2bf(a[0]); r[1] = (short)f2bf(a[1]);
    r[2] = (short)f2bf(a[2]); r[3] = (short)f2bf(a[3]);
    r[4] = (short)f2bf(b[0]); r[5] = (short)f2bf(b[1]);
    r[6] = (short)f2bf(b[2]); r[7] = (short)f2bf(b[3]);
    return r;
}

// ---------------------------------------------------------------------------
// Setup: swizzle eW1 (272x16) and eW2 (16x16) per layer (fp32 in) into bf16
// MFMA B-fragment lane order. B[k][n]: lane = 16*quad + n holds k = quad*8+j.
// w1s: [layer][t(0..8)][lane(64)][j(8)] bf16; K padded 272->288 with 0.
// w2s: [layer][lane(64)][j(8)] bf16; K padded 16->32 with 0.
// ---------------------------------------------------------------------------
__global__ void swizzle_weights(const float* __restrict__ eW1,
                                const float* __restrict__ eW2,
                                ushort_t* __restrict__ w1s,
                                ushort_t* __restrict__ w2s) {
    int id = blockIdx.x * 256 + threadIdx.x;
    if (id >= NLAYERS * 10 * 64) return;
    int lane = id & 63;
    int t10 = id >> 6;            // layer*10 + t
    int layer = t10 / 10, t = t10 % 10;
    int n = lane & 15, quad = lane >> 4;
    if (t < 9) {
        ushort_t* dst = w1s + ((size_t)(layer * 9 + t) * 64 + lane) * 8;
        #pragma unroll
        for (int j = 0; j < 8; ++j) {
            int k = t * 32 + quad * 8 + j;
            dst[j] = (k < 2 * DIM + EDIM)
                       ? f2bf(eW1[((size_t)layer * 272 + k) * 16 + n])
                       : (ushort_t)0;
        }
    } else {
        ushort_t* dst = w2s + ((size_t)layer * 64 + lane) * 8;
        #pragma unroll
        for (int j = 0; j < 8; ++j) {
            int k = quad * 8 + j;
            dst[j] = (k < EDIM) ? f2bf(eW2[((size_t)layer * 16 + k) * 16 + n])
                                : (ushort_t)0;
        }
    }
}

// ---------------------------------------------------------------------------
// LayerNorm step: one wave per node (row of 128 fp32). fp32 throughout.
// sin may equal sout (in-place): each wave fully reads its row (data dep)
// before storing, and rows are wave-exclusive.
// ---------------------------------------------------------------------------
__global__ __launch_bounds__(256) void ln_step(const float* __restrict__ sin,
                                               float* __restrict__ sout,
                                               const float* __restrict__ w,
                                               const float* __restrict__ b) {
    int wv = threadIdx.x >> 6, lane = threadIdx.x & 63;
    int node = blockIdx.x * 4 + wv;                 // N divisible by 4
    const float* row = sin + (size_t)node * DIM;
    int f0 = lane * 2;
    float2 x = *(const float2*)(row + f0);
    float s = x.x + x.y;
    #pragma unroll
    for (int off = 32; off; off >>= 1) s += __shfl_xor(s, off, 64);
    float mu = s * (1.0f / DIM);
    float d0 = x.x - mu, d1 = x.y - mu;
    float v = d0 * d0 + d1 * d1;
    #pragma unroll
    for (int off = 32; off; off >>= 1) v += __shfl_xor(v, off, 64);
    float rs = rsqrtf(v * (1.0f / DIM) + 1e-5f);
    float2 o;
    o.x = d0 * rs * w[f0]     + b[f0];
    o.y = d1 * rs * w[f0 + 1] + b[f0 + 1];
    *(float2*)(sout + (size_t)node * DIM + f0) = o;
}

// ---------------------------------------------------------------------------
// Edge MLP for one layer. Each wave handles a 16-edge tile:
//   h1 = silu([s[src]|s[dst]|ea] @ W1 + b1)   via 9 mfma_f32_16x16x32_bf16
//   ea' = h1 @ W2 + b2                        via 1 mfma (K zero-padded)
// fp32 rows gathered from global, converted to bf16 A-frags in registers.
// h1 C-layout -> A-layout transpose through LDS (bf16, stride 24).
// ea_src may alias ea_dst (in-place): every lane's store value data-depends
// on this tile's loads, and tiles are wave-exclusive.
// ---------------------------------------------------------------------------
__global__ __launch_bounds__(256) void edge_mlp(
        const float* __restrict__ splane,     // [N][128] fp32 (post-LN)
        const float* __restrict__ ea_src,     // [E][16] fp32
        float* __restrict__ ea_dst,           // [E][16] fp32
        const int* __restrict__ ei,           // [2][E] int32
        const ushort_t* __restrict__ w1s,     // this layer's swizzled W1 frags
        const float* __restrict__ eb1,        // [16] fp32
        const ushort_t* __restrict__ w2s,     // this layer's swizzled W2 frag
        const float* __restrict__ eb2,        // [16] fp32
        int nTiles) {
    __shared__ ushort_t h1lds[4][16 * 24];
    const int tid = threadIdx.x;
    const int wv = tid >> 6, lane = tid & 63;
    const int m = lane & 15, quad = lane >> 4;

    // Preload B fragments for this layer (reused across all tiles)
    bf16x8 b1f[9];
    #pragma unroll
    for (int t = 0; t < 9; ++t)
        b1f[t] = *(const bf16x8*)(w1s + ((size_t)t * 64 + lane) * 8);
    bf16x8 b2f = *(const bf16x8*)(w2s + (size_t)lane * 8);
    const float bias1 = eb1[m];
    const float bias2 = eb2[m];
    const bf16x8 zf = {0, 0, 0, 0, 0, 0, 0, 0};

    for (int tile = blockIdx.x; tile < nTiles; tile += gridDim.x) {
        const int ebase = tile * 64 + wv * 16;
        const int e_m = ebase + m;               // this lane's A-row edge
        const int src = ei[e_m];
        const int dst = ei[N_EDGES + e_m];

        f32x4 acc = {0.f, 0.f, 0.f, 0.f};
        const float* sp_s = splane + (size_t)src * DIM + quad * 8;
        const float* sp_d = splane + (size_t)dst * DIM + quad * 8;
        #pragma unroll
        for (int t = 0; t < 4; ++t) {
            f32x4 a = *(const f32x4*)(sp_s + t * 32);
            f32x4 b = *(const f32x4*)(sp_s + t * 32 + 4);
            acc = __builtin_amdgcn_mfma_f32_16x16x32_bf16(cvt8(a, b), b1f[t],
                                                          acc, 0, 0, 0);
        }
        #pragma unroll
        for (int t = 0; t < 4; ++t) {
            f32x4 a = *(const f32x4*)(sp_d + t * 32);
            f32x4 b = *(const f32x4*)(sp_d + t * 32 + 4);
            acc = __builtin_amdgcn_mfma_f32_16x16x32_bf16(cvt8(a, b), b1f[4 + t],
                                                          acc, 0, 0, 0);
        }
        bf16x8 a8 = zf;
        if (quad < 2) {   // k-local 0..15 = ea features, rest zero-padded
            const float* ep = ea_src + (size_t)e_m * EDIM + quad * 8;
            a8 = cvt8(*(const f32x4*)ep, *(const f32x4*)(ep + 4));
        }
        acc = __builtin_amdgcn_mfma_f32_16x16x32_bf16(a8, b1f[8], acc, 0, 0, 0);

        // bias + silu; C layout: col(n)=lane&15, row(edge)=quad*4+r
        ushort_t* hl = h1lds[wv];
        #pragma unroll
        for (int r = 0; r < 4; ++r) {
            float xx = acc[r] + bias1;
            float h = xx / (1.0f + __expf(-xx));   // silu
            hl[(quad * 4 + r) * 24 + m] = f2bf(h);
        }
        __syncthreads();

        bf16x8 a2 = zf;
        if (quad < 2)
            a2 = *(const bf16x8*)(hl + m * 24 + quad * 8);
        f32x4 acc2 = {0.f, 0.f, 0.f, 0.f};
        acc2 = __builtin_amdgcn_mfma_f32_16x16x32_bf16(a2, b2f, acc2, 0, 0, 0);

        #pragma unroll
        for (int r = 0; r < 4; ++r)
            ea_dst[(size_t)(ebase + quad * 4 + r) * EDIM + m] = acc2[r] + bias2;
        __syncthreads();   // protect h1lds before next tile's writes
    }
}

// ---------------------------------------------------------------------------
extern "C" void kernel_launch(void* const* d_in, const int* in_sizes, int n_in,
                              void* d_out, int out_size, void* d_ws, size_t ws_size,
                              hipStream_t stream) {
    const float* s_in  = (const float*)d_in[0];     // [N][128] fp32
    const int*   ei    = (const int*)d_in[1];       // [2][E] int32
    const float* ea_in = (const float*)d_in[2];     // [E][16] fp32
    // d_in[3] = batch: dead (only feeds discarded `out`)
    const float* lnw = (const float*)d_in[4];       // [5][128]
    const float* lnb = (const float*)d_in[5];
    const float* eW1 = (const float*)d_in[6];       // [5][272][16]
    const float* eb1 = (const float*)d_in[7];       // [5][16]
    const float* eW2 = (const float*)d_in[8];       // [5][16][16]
    const float* eb2 = (const float*)d_in[9];
    // d_in[10..13] (nW1,nb1,nW2,nb2): dead — node MLP output is discarded.

    float* out_s  = (float*)d_out;                          // [N][128]
    float* out_ea = (float*)d_out + (size_t)N_NODES * DIM;  // [E][16]

    ushort_t* w1s = (ushort_t*)d_ws;                    // 5*9*64*8 bf16 = 46080 B
    ushort_t* w2s = w1s + (size_t)NLAYERS * 9 * 64 * 8; // 5*64*8 bf16 = 5120 B

    swizzle_weights<<<13, 256, 0, stream>>>(eW1, eW2, w1s, w2s);

    const int nTiles = N_EDGES / 64;   // 25000
    for (int i = 0; i < NLAYERS; ++i) {
        // s <- LN(s); layer 0 reads pristine input, then in-place on d_out.s
        ln_step<<<N_NODES / 4, 256, 0, stream>>>(
            i == 0 ? s_in : out_s, out_s, lnw + i * DIM, lnb + i * DIM);
        // ea <- MLP(s[src], s[dst], ea); in-place on d_out.ea after layer 0
        edge_mlp<<<2048, 256, 0, stream>>>(
            out_s, i == 0 ? ea_in : out_ea, out_ea, ei,
            w1s + (size_t)i * 9 * 64 * 8, eb1 + i * EDIM,
            w2s + (size_t)i * 64 * 8,     eb2 + i * EDIM,
            nTiles);
    }
}

// Round 3
// 546.210 us; speedup vs baseline: 2.8510x; 2.8510x over previous
//
#include <hip/hip_runtime.h>

// Problem constants (fixed by the reference)
#define N_NODES 100000
#define N_EDGES 1600000
#define DIM     128
#define EDIM    16
#define NLAYERS 5

typedef unsigned short ushort_t;
typedef short bf16x8 __attribute__((ext_vector_type(8)));   // 8 bf16 in 4 VGPRs
typedef float f32x4  __attribute__((ext_vector_type(4)));

__device__ __forceinline__ float bf2f(ushort_t u) {
    union { unsigned int i; float f; } c; c.i = ((unsigned int)u) << 16; return c.f;
}
__device__ __forceinline__ ushort_t f2bf(float f) {
    union { float f; unsigned int i; } c; c.f = f;
    unsigned int r = c.i + 0x7fffu + ((c.i >> 16) & 1u);   // RNE
    return (ushort_t)(r >> 16);
}
__device__ __forceinline__ bf16x8 cvt8(f32x4 a, f32x4 b) {
    bf16x8 r;
    r[0] = (short)f2bf(a[0]); r[1] = (short)f2bf(a[1]);
    r[2] = (short)f2bf(a[2]); r[3] = (short)f2bf(a[3]);
    r[4] = (short)f2bf(b[0]); r[5] = (short)f2bf(b[1]);
    r[6] = (short)f2bf(b[2]); r[7] = (short)f2bf(b[3]);
    return r;
}

// ---------------------------------------------------------------------------
// Swizzle eW1 (272x16) / eW2 (16x16) per layer (fp32) into bf16 B-fragments.
// B[k][n]: lane = 16*quad + n holds k = quad*8 + j.
// w1s: [layer][t(0..8)][lane][8]; t0..3 = W1a (k 0..127, the s_src block),
//      t4..7 = W1b (k 128..255, s_dst), t8 = W1c (k 256..271, ea; zero-pad).
// w2s: [layer][lane][8]; K padded 16->32.
// ---------------------------------------------------------------------------
__global__ void swizzle_weights(const float* __restrict__ eW1,
                                const float* __restrict__ eW2,
                                ushort_t* __restrict__ w1s,
                                ushort_t* __restrict__ w2s) {
    int id = blockIdx.x * 256 + threadIdx.x;
    if (id >= NLAYERS * 10 * 64) return;
    int lane = id & 63;
    int t10 = id >> 6;
    int layer = t10 / 10, t = t10 % 10;
    int n = lane & 15, quad = lane >> 4;
    if (t < 9) {
        ushort_t* dst = w1s + ((size_t)(layer * 9 + t) * 64 + lane) * 8;
        #pragma unroll
        for (int j = 0; j < 8; ++j) {
            int k = t * 32 + quad * 8 + j;
            dst[j] = (k < 2 * DIM + EDIM)
                       ? f2bf(eW1[((size_t)layer * 272 + k) * 16 + n])
                       : (ushort_t)0;
        }
    } else {
        ushort_t* dst = w2s + ((size_t)layer * 64 + lane) * 8;
        #pragma unroll
        for (int j = 0; j < 8; ++j) {
            int k = quad * 8 + j;
            dst[j] = (k < EDIM) ? f2bf(eW2[((size_t)layer * 16 + k) * 16 + n])
                                : (ushort_t)0;
        }
    }
}

// ---------------------------------------------------------------------------
// Fused LayerNorm chain + per-node projections. One wave per 16 nodes; each
// node's 128-float row lives in registers across layers l0..l1-1:
//   for each layer: s = LN(s);  u_l = s @ W1a_l;  v_l = s @ W1b_l  (bf16 out)
// Finally stores s (fp32). sin may equal sout (row-exclusive, full read
// before store). u/v slot for layer li is u_buf + (li-l0)*N*16.
// Register layout doubles as MFMA A-layout: lane(m,quad) holds row (tile*16+m),
// k = t*32 + quad*8 + j.
// ---------------------------------------------------------------------------
__global__ __launch_bounds__(256) void ln_uv(
        const float* __restrict__ sin, float* __restrict__ sout,
        const float* __restrict__ lnw, const float* __restrict__ lnb, // [5][128]
        const ushort_t* __restrict__ w1s,                             // all layers
        ushort_t* __restrict__ u_buf, ushort_t* __restrict__ v_buf,
        int l0, int l1) {
    const int wv = threadIdx.x >> 6, lane = threadIdx.x & 63;
    const int m = lane & 15, quad = lane >> 4;
    const int tile = blockIdx.x * 4 + wv;
    if (tile >= N_NODES / 16) return;           // 6250 tiles exactly
    const int node = tile * 16 + m;

    float x[32];
    {
        const float* row = sin + (size_t)node * DIM + quad * 8;
        #pragma unroll
        for (int t = 0; t < 4; ++t) {
            f32x4 a = *(const f32x4*)(row + t * 32);
            f32x4 b = *(const f32x4*)(row + t * 32 + 4);
            #pragma unroll
            for (int j = 0; j < 4; ++j) { x[t * 8 + j] = a[j]; x[t * 8 + 4 + j] = b[j]; }
        }
    }

    for (int li = l0; li < l1; ++li) {
        // --- LayerNorm (fp32, row spread across the 4 quads of lanes w/ same m)
        float s = 0.f;
        #pragma unroll
        for (int k = 0; k < 32; ++k) s += x[k];
        s += __shfl_xor(s, 16); s += __shfl_xor(s, 32);
        float mu = s * (1.0f / DIM);
        float ss = 0.f;
        #pragma unroll
        for (int k = 0; k < 32; ++k) { float d = x[k] - mu; ss += d * d; }
        ss += __shfl_xor(ss, 16); ss += __shfl_xor(ss, 32);
        float rs = rsqrtf(ss * (1.0f / DIM) + 1e-5f);

        const float* w = lnw + (size_t)li * DIM + quad * 8;
        const float* b = lnb + (size_t)li * DIM + quad * 8;
        f32x4 au = {0.f, 0.f, 0.f, 0.f}, av = {0.f, 0.f, 0.f, 0.f};
        #pragma unroll
        for (int t = 0; t < 4; ++t) {
            f32x4 wa = *(const f32x4*)(w + t * 32), wb = *(const f32x4*)(w + t * 32 + 4);
            f32x4 ba = *(const f32x4*)(b + t * 32), bb = *(const f32x4*)(b + t * 32 + 4);
            #pragma unroll
            for (int j = 0; j < 4; ++j) {
                x[t * 8 + j]     = (x[t * 8 + j]     - mu) * rs * wa[j] + ba[j];
                x[t * 8 + 4 + j] = (x[t * 8 + 4 + j] - mu) * rs * wb[j] + bb[j];
            }
            f32x4 ya, yb;
            #pragma unroll
            for (int j = 0; j < 4; ++j) { ya[j] = x[t * 8 + j]; yb[j] = x[t * 8 + 4 + j]; }
            bf16x8 af = cvt8(ya, yb);
            bf16x8 bu = *(const bf16x8*)(w1s + ((size_t)(li * 9 + t)     * 64 + lane) * 8);
            bf16x8 bv = *(const bf16x8*)(w1s + ((size_t)(li * 9 + 4 + t) * 64 + lane) * 8);
            au = __builtin_amdgcn_mfma_f32_16x16x32_bf16(af, bu, au, 0, 0, 0);
            av = __builtin_amdgcn_mfma_f32_16x16x32_bf16(af, bv, av, 0, 0, 0);
        }
        // C layout: row(node-local) = quad*4+r, col(feature) = m
        ushort_t* us = u_buf + (size_t)(li - l0) * N_NODES * EDIM;
        ushort_t* vs = v_buf + (size_t)(li - l0) * N_NODES * EDIM;
        #pragma unroll
        for (int r = 0; r < 4; ++r) {
            int nd = tile * 16 + quad * 4 + r;
            us[(size_t)nd * EDIM + m] = f2bf(au[r]);
            vs[(size_t)nd * EDIM + m] = f2bf(av[r]);
        }
    }

    float* orow = sout + (size_t)node * DIM + quad * 8;
    #pragma unroll
    for (int t = 0; t < 4; ++t) {
        f32x4 a, b;
        #pragma unroll
        for (int j = 0; j < 4; ++j) { a[j] = x[t * 8 + j]; b[j] = x[t * 8 + 4 + j]; }
        *(f32x4*)(orow + t * 32) = a;
        *(f32x4*)(orow + t * 32 + 4) = b;
    }
}

// ---------------------------------------------------------------------------
// Edge pass, one layer. Per wave-tile of 16 edges:
//   h1 = silu(u[src] + v[dst] + ea@W1c + b1);  ea' = h1@W2 + b2
// Gathers are 32B/endpoint (bf16 u/v rows) instead of 512B s rows.
// ea in/out dtype via template (bf16 workspace between layers).
// In-place safe: each lane's store data-depends on this tile's loads.
// ---------------------------------------------------------------------------
template<int IN_F32, int OUT_F32>
__global__ __launch_bounds__(256) void edge_pass(
        const void* __restrict__ ea_in_, void* __restrict__ ea_out_,
        const int* __restrict__ ei,
        const ushort_t* __restrict__ u_buf, const ushort_t* __restrict__ v_buf,
        const ushort_t* __restrict__ w1c,   // this layer's t=8 frag [64][8]
        const float* __restrict__ eb1,
        const ushort_t* __restrict__ w2f,   // this layer's W2 frag [64][8]
        const float* __restrict__ eb2) {
    __shared__ ushort_t h1lds[4][16 * 24];
    const int wv = threadIdx.x >> 6, lane = threadIdx.x & 63;
    const int m = lane & 15, quad = lane >> 4;

    const bf16x8 bc  = *(const bf16x8*)(w1c + (size_t)lane * 8);
    const bf16x8 b2f = *(const bf16x8*)(w2f + (size_t)lane * 8);
    const float bias1 = eb1[m];
    const float bias2 = eb2[m];
    const bf16x8 zf = {0, 0, 0, 0, 0, 0, 0, 0};
    const int nTiles = N_EDGES / 64;

    for (int tile = blockIdx.x; tile < nTiles; tile += gridDim.x) {
        const int ebase = tile * 64 + wv * 16;
        const int e_m = ebase + m;

        // ea A-frag (K=32 padded; quads 0,1 hold the 16 real features)
        bf16x8 a8 = zf;
        if (IN_F32) {
            if (quad < 2) {
                const float* ep = (const float*)ea_in_ + (size_t)e_m * EDIM + quad * 8;
                a8 = cvt8(*(const f32x4*)ep, *(const f32x4*)(ep + 4));
            }
        } else {
            if (quad < 2)
                a8 = *(const bf16x8*)((const ushort_t*)ea_in_ + (size_t)e_m * EDIM + quad * 8);
        }
        f32x4 acc = {0.f, 0.f, 0.f, 0.f};
        acc = __builtin_amdgcn_mfma_f32_16x16x32_bf16(a8, bc, acc, 0, 0, 0);

        // u[src], v[dst] for the 4 C-rows this lane owns (row = quad*4+r, col m)
        int es[4], ed[4];
        #pragma unroll
        for (int r = 0; r < 4; ++r) {
            es[r] = ei[ebase + quad * 4 + r];
            ed[r] = ei[N_EDGES + ebase + quad * 4 + r];
        }
        ushort_t uu[4], vv[4];
        #pragma unroll
        for (int r = 0; r < 4; ++r) {
            uu[r] = u_buf[(size_t)es[r] * EDIM + m];
            vv[r] = v_buf[(size_t)ed[r] * EDIM + m];
        }
        ushort_t* hl = h1lds[wv];
        #pragma unroll
        for (int r = 0; r < 4; ++r) {
            float xx = acc[r] + bf2f(uu[r]) + bf2f(vv[r]) + bias1;
            float h = xx / (1.0f + __expf(-xx));   // silu
            hl[(quad * 4 + r) * 24 + m] = f2bf(h);
        }
        __syncthreads();

        bf16x8 a2 = zf;
        if (quad < 2) a2 = *(const bf16x8*)(hl + m * 24 + quad * 8);
        f32x4 acc2 = {0.f, 0.f, 0.f, 0.f};
        acc2 = __builtin_amdgcn_mfma_f32_16x16x32_bf16(a2, b2f, acc2, 0, 0, 0);

        #pragma unroll
        for (int r = 0; r < 4; ++r) {
            float yv = acc2[r] + bias2;
            size_t off = (size_t)(ebase + quad * 4 + r) * EDIM + m;
            if (OUT_F32) ((float*)ea_out_)[off] = yv;
            else         ((ushort_t*)ea_out_)[off] = f2bf(yv);
        }
        __syncthreads();   // protect h1lds before next tile's writes
    }
}

// ---------------------------------------------------------------------------
extern "C" void kernel_launch(void* const* d_in, const int* in_sizes, int n_in,
                              void* d_out, int out_size, void* d_ws, size_t ws_size,
                              hipStream_t stream) {
    const float* s_in  = (const float*)d_in[0];     // [N][128] fp32
    const int*   ei    = (const int*)d_in[1];       // [2][E] int32
    const float* ea_in = (const float*)d_in[2];     // [E][16] fp32
    // d_in[3] = batch: dead
    const float* lnw = (const float*)d_in[4];
    const float* lnb = (const float*)d_in[5];
    const float* eW1 = (const float*)d_in[6];       // [5][272][16]
    const float* eb1 = (const float*)d_in[7];
    const float* eW2 = (const float*)d_in[8];       // [5][16][16]
    const float* eb2 = (const float*)d_in[9];
    // d_in[10..13]: dead (node MLP output discarded)

    float* out_s  = (float*)d_out;                          // [N][128]
    float* out_ea = (float*)d_out + (size_t)N_NODES * DIM;  // [E][16]

    ushort_t* w1s = (ushort_t*)d_ws;                     // 5*9*64*8 = 23040 elems
    ushort_t* w2s = w1s + (size_t)NLAYERS * 9 * 64 * 8;  // 5*64*8 = 2560 elems
    ushort_t* uv0 = w2s + (size_t)NLAYERS * 64 * 8;
    const size_t wWords  = (size_t)NLAYERS * 10 * 64 * 8;          // weight elems
    const size_t uvLayer = (size_t)N_NODES * EDIM;                  // 1.6M elems
    const size_t needA = (wWords + 2 * NLAYERS * uvLayer + (size_t)N_EDGES * EDIM) * 2;
    const size_t needB = (wWords + 2 * NLAYERS * uvLayer) * 2;
    const int lnGrid = (N_NODES / 16 + 3) / 4;   // 1563
    const int eGrid = 4096;

    swizzle_weights<<<13, 256, 0, stream>>>(eW1, eW2, w1s, w2s);

    if (ws_size >= needA) {
        // Fused LN chain, ea carried as bf16 in workspace.
        ushort_t* u0 = uv0;
        ushort_t* v0 = u0 + NLAYERS * uvLayer;
        ushort_t* eaw = v0 + NLAYERS * uvLayer;     // [E][16] bf16
        ln_uv<<<lnGrid, 256, 0, stream>>>(s_in, out_s, lnw, lnb, w1s, u0, v0, 0, NLAYERS);
        for (int l = 0; l < NLAYERS; ++l) {
            const ushort_t* w1c = w1s + ((size_t)l * 9 + 8) * 64 * 8;
            const ushort_t* w2l = w2s + (size_t)l * 64 * 8;
            ushort_t* ul = u0 + (size_t)l * uvLayer;
            ushort_t* vl = v0 + (size_t)l * uvLayer;
            if (l == 0)
                edge_pass<1, 0><<<eGrid, 256, 0, stream>>>(ea_in, eaw, ei, ul, vl,
                                                           w1c, eb1 + l * EDIM, w2l, eb2 + l * EDIM);
            else if (l < NLAYERS - 1)
                edge_pass<0, 0><<<eGrid, 256, 0, stream>>>(eaw, eaw, ei, ul, vl,
                                                           w1c, eb1 + l * EDIM, w2l, eb2 + l * EDIM);
            else
                edge_pass<0, 1><<<eGrid, 256, 0, stream>>>(eaw, out_ea, ei, ul, vl,
                                                           w1c, eb1 + l * EDIM, w2l, eb2 + l * EDIM);
        }
    } else if (ws_size >= needB) {
        // Fused LN chain, ea fp32 in-place in d_out.
        ushort_t* u0 = uv0;
        ushort_t* v0 = u0 + NLAYERS * uvLayer;
        ln_uv<<<lnGrid, 256, 0, stream>>>(s_in, out_s, lnw, lnb, w1s, u0, v0, 0, NLAYERS);
        for (int l = 0; l < NLAYERS; ++l) {
            const ushort_t* w1c = w1s + ((size_t)l * 9 + 8) * 64 * 8;
            const ushort_t* w2l = w2s + (size_t)l * 64 * 8;
            edge_pass<1, 1><<<eGrid, 256, 0, stream>>>(
                l == 0 ? (const void*)ea_in : (const void*)out_ea, out_ea, ei,
                u0 + (size_t)l * uvLayer, v0 + (size_t)l * uvLayer,
                w1c, eb1 + l * EDIM, w2l, eb2 + l * EDIM);
        }
    } else {
        // Minimal ws: per-layer u/v slot, ea fp32 in-place, s fp32 in-place.
        ushort_t* u0 = uv0;
        ushort_t* v0 = u0 + uvLayer;
        for (int l = 0; l < NLAYERS; ++l) {
            ln_uv<<<lnGrid, 256, 0, stream>>>(l == 0 ? s_in : out_s, out_s,
                                              lnw, lnb, w1s, u0, v0, l, l + 1);
            const ushort_t* w1c = w1s + ((size_t)l * 9 + 8) * 64 * 8;
            const ushort_t* w2l = w2s + (size_t)l * 64 * 8;
            edge_pass<1, 1><<<eGrid, 256, 0, stream>>>(
                l == 0 ? (const void*)ea_in : (const void*)out_ea, out_ea, ei,
                u0, v0, w1c, eb1 + l * EDIM, w2l, eb2 + l * EDIM);
        }
    }
}